// Round 2
// baseline (56.196 us; speedup 1.0000x reference)
//
#include <hip/hip_runtime.h>
#include <math.h>

// Problem constants
#define T_LEN 512
#define B_DIM 16
#define K_DIM 64
#define N_DIM 64
#define M_DIM 128

// ---------------------------------------------------------------------------
// K1: Bp[k][n] = prod_{i != n} 1/(1 - e^{i(ang_i - ang_n)})
//     using 1/(1-e^{i d}) = 0.5 + 0.5*i*cot(d/2)
// grid 64 blocks (k) x 64 threads (n)
// ---------------------------------------------------------------------------
__global__ void k_bp(const float* __restrict__ theta, float2* __restrict__ bp) {
    int k = blockIdx.x;
    int j = threadIdx.x;
    __shared__ float ang[N_DIM];
    float a = (j < 32) ? theta[k * 32 + j] : -theta[k * 32 + (j - 32)];
    ang[j] = a;
    __syncthreads();
    double pr = 1.0, pi = 0.0;
    for (int i = 0; i < N_DIM; ++i) {
        if (i == j) continue;
        float d = ang[i] - a;          // exact-ish float difference
        float s, c;
        sincosf(0.5f * d, &s, &c);
        float ti = 0.5f * (c / s);     // 0.5*cot(d/2)
        double nr = pr * 0.5 - pi * (double)ti;
        double ni = pr * (double)ti + pi * 0.5;
        pr = nr; pi = ni;
    }
    bp[k * N_DIM + j] = make_float2((float)pr, (float)pi);
}

// ---------------------------------------------------------------------------
// K2: sT[k][n][b] = Bp[k][n] * sum_{u=0}^{510} lam^{510-u} x[u][b][k]
// grid 1024 blocks (b,k) x 256 threads (wave c = time-chunk, lane n)
// 4 chunks of 128 steps combined with lam^{128/256/384} (double squarings).
// ---------------------------------------------------------------------------
__global__ void k_state(const float* __restrict__ x, const float* __restrict__ theta,
                        const float2* __restrict__ bp, float2* __restrict__ sT) {
    int id = blockIdx.x;
    // XCD chunked swizzle: 8 XCDs, 1024 blocks -> 128 logical ids per XCD
    int logical = (id & 7) * 128 + (id >> 3);
    int b = logical >> 6;
    int k = logical & 63;
    int tid = threadIdx.x;
    int c = tid >> 6;   // chunk index == wave index
    int n = tid & 63;

    float a = (n < 32) ? theta[k * 32 + n] : -theta[k * 32 + (n - 32)];
    float li, lr;
    sincosf(a, &li, &lr);   // lam = (lr, li)

    const float* xp = x + b * K_DIM + k;   // x[u] at xp[u*1024]
    float sr = 0.f, si = 0.f;
    int t0 = 128 * c;
    int jstart = (c == 0) ? 1 : 0;         // xc_0 == 0
    for (int j = jstart; j < 128; ++j) {
        float xv = xp[(t0 + j - 1) * (B_DIM * K_DIM)];
        float nr2 = fmaf(lr, sr, fmaf(-li, si, xv));
        float ni2 = fmaf(lr, si, li * sr);
        sr = nr2; si = ni2;
    }
    __shared__ float2 part[4][N_DIM];
    part[c][n] = make_float2(sr, si);
    __syncthreads();
    if (tid < 64) {
        // lam^128 by 7 squarings in double, then ^256, ^384
        double ar = (double)lr, ai = (double)li;
        #pragma unroll
        for (int q = 0; q < 7; ++q) {
            double t1 = ar * ar - ai * ai;
            double t2 = 2.0 * ar * ai;
            ar = t1; ai = t2;
        }
        double b2r = ar * ar - ai * ai, b2i = 2.0 * ar * ai;          // ^256
        double b3r = b2r * ar - b2i * ai, b3i = b2r * ai + b2i * ar;  // ^384
        float2 s0 = part[0][n], s1 = part[1][n], s2 = part[2][n], s3 = part[3][n];
        double gr = b3r * s0.x - b3i * s0.y + b2r * s1.x - b2i * s1.y
                  + ar  * s2.x - ai  * s2.y + (double)s3.x;
        double gi = b3r * s0.y + b3i * s0.x + b2r * s1.y + b2i * s1.x
                  + ar  * s2.y + ai  * s2.x + (double)s3.y;
        float2 bv = bp[k * N_DIM + n];
        float rr = (float)(gr * bv.x - gi * bv.y);
        float ri = (float)(gr * bv.y + gi * bv.x);
        sT[(k * N_DIM + n) * B_DIM + b] = make_float2(rr, ri);
    }
}

// ---------------------------------------------------------------------------
// K3: out[b][m] = (1/K) * ( sum_{k,n} sT[k][n][b] * exp(lnC[k][m][n])
//                           + sum_k x[510][b][k] * D[k][m] ) + Do[m]
// grid 128 blocks (m) x 256 threads
// cplx==0: write real part only (out_size floats = B*M)
// cplx==1: write interleaved float2 (out_size floats = 2*B*M)
// ---------------------------------------------------------------------------
__global__ void k_out(const float* __restrict__ lnCr, const float* __restrict__ lnCi,
                      const float* __restrict__ D, const float* __restrict__ Do_,
                      const float* __restrict__ x, const float2* __restrict__ sT,
                      float* __restrict__ out, int cplx) {
    int m = blockIdx.x;
    int tid = threadIdx.x;
    float accr[B_DIM], acci[B_DIM];
    #pragma unroll
    for (int b = 0; b < B_DIM; ++b) { accr[b] = 0.f; acci[b] = 0.f; }

    for (int it = 0; it < 16; ++it) {
        int p = it * 256 + tid;        // (k,n) pair index
        int k = p >> 6;
        int n = p & 63;
        int ci = k * (M_DIM * N_DIM) + m * N_DIM + n;
        float er = expf(lnCr[ci]);
        float sn, cs;
        sincosf(lnCi[ci], &sn, &cs);
        float cr = er * cs, cim = er * sn;
        const float2* sp = sT + p * B_DIM;
        #pragma unroll
        for (int b = 0; b < B_DIM; ++b) {
            float2 s = sp[b];
            accr[b] = fmaf(s.x, cr, fmaf(-s.y, cim, accr[b]));
            acci[b] = fmaf(s.x, cim, fmaf(s.y, cr, acci[b]));
        }
    }

    __shared__ float2 red[B_DIM][256];
    #pragma unroll
    for (int b = 0; b < B_DIM; ++b) red[b][tid] = make_float2(accr[b], acci[b]);
    __syncthreads();
    // stage 1: 256 threads -> 16 partials per b
    {
        int b = tid >> 4, seg = tid & 15;
        float2 sum = make_float2(0.f, 0.f);
        #pragma unroll
        for (int q = 0; q < 16; ++q) {
            float2 v = red[b][seg * 16 + q];
            sum.x += v.x; sum.y += v.y;
        }
        __syncthreads();               // all reads done before overwrite
        red[b][seg] = sum;
    }
    __syncthreads();
    if (tid < B_DIM) {
        int b = tid;
        float sumr = 0.f, sumi = 0.f;
        #pragma unroll
        for (int q = 0; q < 16; ++q) {
            float2 v = red[b][q];
            sumr += v.x; sumi += v.y;
        }
        // Dx term: x[T-2][b][k] * D[k][m]
        float dx = 0.f;
        const float* xl = x + 510 * (B_DIM * K_DIM) + b * K_DIM;
        #pragma unroll 8
        for (int kk = 0; kk < K_DIM; ++kk)
            dx = fmaf(xl[kk], D[kk * M_DIM + m], dx);
        float outr = (sumr + dx) * (1.0f / 64.0f) + Do_[m];
        float outi = sumi * (1.0f / 64.0f);
        if (cplx) {
            ((float2*)out)[b * M_DIM + m] = make_float2(outr, outi);
        } else {
            out[b * M_DIM + m] = outr;
        }
    }
}

// ---------------------------------------------------------------------------
extern "C" void kernel_launch(void* const* d_in, const int* in_sizes, int n_in,
                              void* d_out, int out_size, void* d_ws, size_t ws_size,
                              hipStream_t stream) {
    const float* x     = (const float*)d_in[0];
    const float* theta = (const float*)d_in[1];
    const float* lnCr  = (const float*)d_in[2];
    const float* lnCi  = (const float*)d_in[3];
    const float* D     = (const float*)d_in[4];
    const float* Do_   = (const float*)d_in[5];

    float2* bp = (float2*)d_ws;                    // 64*64 float2   = 32 KB
    float2* sT = bp + K_DIM * N_DIM;               // 4096*16 float2 = 512 KB

    // out_size == B*M (2048): real-part-only float32 output
    // out_size == 2*B*M (4096): interleaved complex64 viewed as float32
    int cplx = (out_size >= 2 * B_DIM * M_DIM) ? 1 : 0;

    k_bp   <<<K_DIM, N_DIM, 0, stream>>>(theta, bp);
    k_state<<<B_DIM * K_DIM, 256, 0, stream>>>(x, theta, bp, sT);
    k_out  <<<M_DIM, 256, 0, stream>>>(lnCr, lnCi, D, Do_, x, sT, (float*)d_out, cplx);
}

// Round 3
// 47.301 us; speedup vs baseline: 1.1880x; 1.1880x over previous
//
#include <hip/hip_runtime.h>
#include <math.h>

// Problem constants
#define T_LEN 512
#define B_DIM 16
#define K_DIM 64
#define N_DIM 64
#define M_DIM 128

// ---------------------------------------------------------------------------
// K_prep (fused):
//   blocks 0..63   : Bp[k][n] = prod_{i != n} 1/(1 - e^{i(ang_i - ang_n)})
//                    via 1/(1-e^{i d}) = 0.5 + 0.5*i*cot(d/2)
//   blocks 64..191 : transpose x[T=512][B*K=1024] -> xt[B*K=1024][T=512]
//                    (64x64 tiles through LDS, coalesced both ways)
// 256 threads
// ---------------------------------------------------------------------------
__global__ void k_prep(const float* __restrict__ theta, const float* __restrict__ x,
                       float2* __restrict__ bp, float* __restrict__ xt) {
    __shared__ float tile[64][65];
    int id = blockIdx.x;
    int tid = threadIdx.x;

    if (id < 64) {
        // ---- Bp for k = id ----
        int k = id;
        if (tid < 64) {
            float a = (tid < 32) ? theta[k * 32 + tid] : -theta[k * 32 + (tid - 32)];
            tile[0][tid] = a;
        }
        __syncthreads();
        if (tid < 64) {
            float a = tile[0][tid];
            double pr = 1.0, pi = 0.0;
            for (int i = 0; i < N_DIM; ++i) {
                if (i == tid) continue;
                float d = tile[0][i] - a;
                float s, c;
                sincosf(0.5f * d, &s, &c);
                float ti = 0.5f * (c / s);     // 0.5*cot(d/2)
                double nr = pr * 0.5 - pi * (double)ti;
                double ni = pr * (double)ti + pi * 0.5;
                pr = nr; pi = ni;
            }
            bp[k * N_DIM + tid] = make_float2((float)pr, (float)pi);
        }
    } else {
        // ---- transpose tile ----
        int t = id - 64;                  // 0..127
        int u0 = (t >> 4) << 6;           // 8 u-tiles of 64
        int c0 = (t & 15) << 6;           // 16 col-tiles of 64
        int tr = tid >> 6;                // 0..3
        int tc = tid & 63;                // 0..63
        #pragma unroll
        for (int p = 0; p < 16; ++p) {
            int r = 4 * p + tr;
            tile[r][tc] = x[(u0 + r) * (B_DIM * K_DIM) + c0 + tc];
        }
        __syncthreads();
        #pragma unroll
        for (int p = 0; p < 16; ++p) {
            int r = 4 * p + tr;
            xt[(size_t)(c0 + r) * T_LEN + u0 + tc] = tile[tc][r];
        }
    }
}

// ---------------------------------------------------------------------------
// K2: sT[k][n][b] = Bp[k][n] * sum_{u=0}^{510} lam^{510-u} x[u][b][k]
// grid 1024 blocks (b,k) x 256 threads (wave c = time-chunk, lane n)
// x comes in transposed as xt[b*64+k][u] -> one coalesced 2KB LDS stage,
// recurrence reads LDS (broadcast, conflict-free).
// 4 chunks of 128 steps combined with lam^{128/256/384} (double squarings).
// ---------------------------------------------------------------------------
__global__ void k_state(const float* __restrict__ xt, const float* __restrict__ theta,
                        const float2* __restrict__ bp, float2* __restrict__ sT) {
    int id = blockIdx.x;
    // XCD chunked swizzle: 8 XCDs, 1024 blocks -> 128 logical ids per XCD
    int logical = (id & 7) * 128 + (id >> 3);
    int b = logical >> 6;
    int k = logical & 63;
    int tid = threadIdx.x;
    int c = tid >> 6;   // chunk index == wave index
    int n = tid & 63;

    __shared__ float xs[T_LEN];
    __shared__ float2 part[4][N_DIM];

    // coalesced stage: 512 floats = 256 float2
    ((float2*)xs)[tid] = ((const float2*)(xt + (size_t)logical * T_LEN))[tid];

    float a = (n < 32) ? theta[k * 32 + n] : -theta[k * 32 + (n - 32)];
    float li, lr;
    sincosf(a, &li, &lr);   // lam = (lr, li)
    __syncthreads();

    float sr = 0.f, si = 0.f;
    int base = 128 * c - 1;
    int jstart = (c == 0) ? 1 : 0;         // xc_0 == 0
    #pragma unroll 8
    for (int j = jstart; j < 128; ++j) {
        float xv = xs[base + j];
        float nr2 = fmaf(lr, sr, fmaf(-li, si, xv));
        float ni2 = fmaf(lr, si, li * sr);
        sr = nr2; si = ni2;
    }
    part[c][n] = make_float2(sr, si);
    __syncthreads();
    if (tid < 64) {
        // lam^128 by 7 squarings in double, then ^256, ^384
        double ar = (double)lr, ai = (double)li;
        #pragma unroll
        for (int q = 0; q < 7; ++q) {
            double t1 = ar * ar - ai * ai;
            double t2 = 2.0 * ar * ai;
            ar = t1; ai = t2;
        }
        double b2r = ar * ar - ai * ai, b2i = 2.0 * ar * ai;          // ^256
        double b3r = b2r * ar - b2i * ai, b3i = b2r * ai + b2i * ar;  // ^384
        float2 s0 = part[0][n], s1 = part[1][n], s2 = part[2][n], s3 = part[3][n];
        double gr = b3r * s0.x - b3i * s0.y + b2r * s1.x - b2i * s1.y
                  + ar  * s2.x - ai  * s2.y + (double)s3.x;
        double gi = b3r * s0.y + b3i * s0.x + b2r * s1.y + b2i * s1.x
                  + ar  * s2.y + ai  * s2.x + (double)s3.y;
        float2 bv = bp[k * N_DIM + n];
        float rr = (float)(gr * bv.x - gi * bv.y);
        float ri = (float)(gr * bv.y + gi * bv.x);
        sT[(k * N_DIM + n) * B_DIM + b] = make_float2(rr, ri);
    }
}

// ---------------------------------------------------------------------------
// K3: out[b][m] = (1/K) * ( sum_{k,n} sT[k][n][b] * exp(lnC[k][m][n])
//                           + sum_k x[510][b][k] * D[k][m] ) + Do[m]
// grid 128 blocks (m) x 256 threads
// cplx==0: write real part only (out_size floats = B*M)
// cplx==1: write interleaved float2 (out_size floats = 2*B*M)
// ---------------------------------------------------------------------------
__global__ void k_out(const float* __restrict__ lnCr, const float* __restrict__ lnCi,
                      const float* __restrict__ D, const float* __restrict__ Do_,
                      const float* __restrict__ x, const float2* __restrict__ sT,
                      float* __restrict__ out, int cplx) {
    int m = blockIdx.x;
    int tid = threadIdx.x;
    float accr[B_DIM], acci[B_DIM];
    #pragma unroll
    for (int b = 0; b < B_DIM; ++b) { accr[b] = 0.f; acci[b] = 0.f; }

    for (int it = 0; it < 16; ++it) {
        int p = it * 256 + tid;        // (k,n) pair index
        int k = p >> 6;
        int n = p & 63;
        int ci = k * (M_DIM * N_DIM) + m * N_DIM + n;
        float er = expf(lnCr[ci]);
        float sn, cs;
        sincosf(lnCi[ci], &sn, &cs);
        float cr = er * cs, cim = er * sn;
        const float2* sp = sT + p * B_DIM;
        #pragma unroll
        for (int b = 0; b < B_DIM; ++b) {
            float2 s = sp[b];
            accr[b] = fmaf(s.x, cr, fmaf(-s.y, cim, accr[b]));
            acci[b] = fmaf(s.x, cim, fmaf(s.y, cr, acci[b]));
        }
    }

    __shared__ float2 red[B_DIM][256];
    #pragma unroll
    for (int b = 0; b < B_DIM; ++b) red[b][tid] = make_float2(accr[b], acci[b]);
    __syncthreads();
    // stage 1: 256 threads -> 16 partials per b
    {
        int b = tid >> 4, seg = tid & 15;
        float2 sum = make_float2(0.f, 0.f);
        #pragma unroll
        for (int q = 0; q < 16; ++q) {
            float2 v = red[b][seg * 16 + q];
            sum.x += v.x; sum.y += v.y;
        }
        __syncthreads();               // all reads done before overwrite
        red[b][seg] = sum;
    }
    __syncthreads();
    if (tid < B_DIM) {
        int b = tid;
        float sumr = 0.f, sumi = 0.f;
        #pragma unroll
        for (int q = 0; q < 16; ++q) {
            float2 v = red[b][q];
            sumr += v.x; sumi += v.y;
        }
        // Dx term: x[T-2][b][k] * D[k][m]
        float dx = 0.f;
        const float* xl = x + 510 * (B_DIM * K_DIM) + b * K_DIM;
        #pragma unroll 8
        for (int kk = 0; kk < K_DIM; ++kk)
            dx = fmaf(xl[kk], D[kk * M_DIM + m], dx);
        float outr = (sumr + dx) * (1.0f / 64.0f) + Do_[m];
        float outi = sumi * (1.0f / 64.0f);
        if (cplx) {
            ((float2*)out)[b * M_DIM + m] = make_float2(outr, outi);
        } else {
            out[b * M_DIM + m] = outr;
        }
    }
}

// ---------------------------------------------------------------------------
extern "C" void kernel_launch(void* const* d_in, const int* in_sizes, int n_in,
                              void* d_out, int out_size, void* d_ws, size_t ws_size,
                              hipStream_t stream) {
    const float* x     = (const float*)d_in[0];
    const float* theta = (const float*)d_in[1];
    const float* lnCr  = (const float*)d_in[2];
    const float* lnCi  = (const float*)d_in[3];
    const float* D     = (const float*)d_in[4];
    const float* Do_   = (const float*)d_in[5];

    float2* bp = (float2*)d_ws;                    // 64*64 float2    =  32 KB
    float2* sT = bp + K_DIM * N_DIM;               // 4096*16 float2  = 512 KB
    float*  xt = (float*)(sT + K_DIM * N_DIM * B_DIM);  // 1024*512 f = 2 MB

    // out_size == B*M (2048): real-part-only float32 output
    // out_size == 2*B*M (4096): interleaved complex64 viewed as float32
    int cplx = (out_size >= 2 * B_DIM * M_DIM) ? 1 : 0;

    k_prep <<<192, 256, 0, stream>>>(theta, x, bp, xt);
    k_state<<<B_DIM * K_DIM, 256, 0, stream>>>(xt, theta, bp, sT);
    k_out  <<<M_DIM, 256, 0, stream>>>(lnCr, lnCi, D, Do_, x, sT, (float*)d_out, cplx);
}